// Round 3
// baseline (845.733 us; speedup 1.0000x reference)
//
#include <hip/hip_runtime.h>
#include <hip/hip_bf16.h>
#include <stdint.h>

// Problem constants
#define NN 32768
#define KNBR 32
#define FDIM 4
#define WDIM 256
#define TPB_TILES 8   // 64-edge-row tiles per block; grid = 16384/8 = 2048

typedef __attribute__((ext_vector_type(8))) short short8;
typedef __attribute__((ext_vector_type(4))) float f32x4;

__device__ __forceinline__ unsigned int f2bf(float x) {
    union { float f; unsigned int u; } c; c.f = x;
    return (c.u + 0x7FFFu + ((c.u >> 16) & 1u)) >> 16;
}
__device__ __forceinline__ unsigned int pk2(float a, float b) {
    return f2bf(a) | (f2bf(b) << 16);
}
// cheap round-half-up bf16 pack: 4 ops vs ~9 for RNE (bias negligible vs threshold)
__device__ __forceinline__ unsigned int pkr(float a, float b) {
    unsigned ua = __float_as_uint(a) + 0x8000u;
    unsigned ub = __float_as_uint(b) + 0x8000u;
    return (ua >> 16) | (ub & 0xFFFF0000u);
}
__device__ __forceinline__ float silu_f(float x) {
    return x / (1.0f + __expf(-x));
}

// ---------------------------------------------------------------------------
// Kernel 1: convert W_f2, W_nb, W_c (f32 row-major [256][256]) into bf16
// MFMA B-fragment layout: frag q = (kt*16 + nt)*64 + lane holds
// B[k = kt*32 + (lane>>4)*8 + i][col = nt*16 + (lane&15)], i=0..7, 16B/frag.
// ---------------------------------------------------------------------------
__global__ void prep_weights(const float* __restrict__ Wf2,
                             const float* __restrict__ Wnb,
                             const float* __restrict__ Wc,
                             uint4* __restrict__ ws_out) {
    int t = blockIdx.x * 256 + threadIdx.x;   // 0..24575
    int w = t >> 13;
    int q = t & 8191;
    int kt = q >> 10;
    int nt = (q >> 6) & 15;
    int lane = q & 63;
    int k0 = kt * 32 + ((lane >> 4) << 3);
    int col = nt * 16 + (lane & 15);
    const float* src = (w == 0) ? Wf2 : (w == 1) ? Wnb : Wc;
    const float* p = src + (size_t)k0 * 256 + col;
    uint4 o;
    o.x = pk2(p[0],        p[256]);
    o.y = pk2(p[512],      p[768]);
    o.z = pk2(p[1024],     p[1280]);
    o.w = pk2(p[1536],     p[1792]);
    ws_out[t] = o;
}

// ---------------------------------------------------------------------------
// Kernel 2: persistent-weight fused edge pipeline.
// Block = 512 thr (8 waves), processes TPB_TILES tiles of 64 edge rows.
// Wave w owns cols [w*32, w*32+32); B-frags of W_f2 AND W_nb live in regs
// (128 VGPR) for the whole kernel -> zero weight staging in the loop.
// Per tile: stage f=silu(diff@Wf1+b1) and E=bf16(nbr) A-frags into dbuf LDS,
// dual-acc MFMA (Phi, H), gate+rowsum epilogue, ONE barrier.
// ---------------------------------------------------------------------------
__global__ __launch_bounds__(512, 2) void msg_kernel(
        const float* __restrict__ nbr,    // h_neighbors [N*K, 256]
        const float* __restrict__ diff,   // differences [N*K, 4]
        const float* __restrict__ Wf1,    // [4,256]
        const float* __restrict__ b1,     // [256]
        const float* __restrict__ b2,     // b_f2 [256]
        const float* __restrict__ bnb,    // b_nb [256]
        const uint4* __restrict__ wf2_g,  // frag bf16, 8192 uint4
        const uint4* __restrict__ wnb_g,  // frag bf16, 8192 uint4
        float* __restrict__ msg_out)      // [N,256] f32
{
    __shared__ uint4 fbuf[2][2048];   // 64KB: f A-frags, [mt*8+kti]*64+slot
    __shared__ uint4 ebuf[2][2048];   // 64KB: E A-frags
    __shared__ float wf1_s[1024];     // 4KB
    __shared__ float b1_s[256];       // 1KB

    const int tid  = threadIdx.x;
    const int lane = tid & 63;
    const int wid  = tid >> 6;     // col slice / f k-tile
    const int srow = tid >> 3;     // E staging: row 0..63
    const int skti = tid & 7;      // E staging: k-tile 0..7
    const int smt  = srow >> 4;
    const int sfr  = srow & 15;
    const int mtf  = lane >> 4;    // f staging: row = lane
    const int frf  = lane & 15;

    for (int i = tid; i < 1024; i += 512) wf1_s[i] = Wf1[i];
    if (tid < 256) b1_s[tid] = b1[tid];

    // persistent register B-fragments (32 x short8 = 128 VGPR)
    const short8* wf2p = (const short8*)wf2_g;
    const short8* wnbp = (const short8*)wnb_g;
    short8 bF[8][2], bN[8][2];
    #pragma unroll
    for (int kti = 0; kti < 8; ++kti) {
        #pragma unroll
        for (int nt = 0; nt < 2; ++nt) {
            const int idx = (kti * 16 + wid * 2 + nt) * 64 + lane;
            bF[kti][nt] = wf2p[idx];
            bN[kti][nt] = wnbp[idx];
        }
    }
    float vb2[2], vbn[2];
    #pragma unroll
    for (int nt = 0; nt < 2; ++nt) {
        const int col = wid * 32 + nt * 16 + frf;
        vb2[nt] = b2[col];
        vbn[nt] = bnb[col];
    }

    f32x4 accP[4][2], accH[4][2];
    #pragma unroll
    for (int mt = 0; mt < 4; ++mt)
        #pragma unroll
        for (int nt = 0; nt < 2; ++nt) {
            accP[mt][nt] = (f32x4){0.f,0.f,0.f,0.f};
            accH[mt][nt] = (f32x4){0.f,0.f,0.f,0.f};
        }

    const int tbase = blockIdx.x * TPB_TILES;

    // f staging: thread handles row=lane, k in [wid*32, wid*32+32).
    // wf1/b1 reads are WAVE-UNIFORM float4 broadcasts (wid uniform).
    auto stage_f = [&](int bsel, float4 d4) {
        uint4* fb = fbuf[bsel];
        const float4* w4 = (const float4*)wf1_s;
        const float4* b4 = (const float4*)b1_s;
        #pragma unroll
        for (int g = 0; g < 4; ++g) {
            const int o = wid * 8 + g * 2;
            float4 ba = b4[o],      bb = b4[o+1];
            float4 w0a = w4[o],     w0b = w4[o+1];
            float4 w1a = w4[64+o],  w1b = w4[64+o+1];
            float4 w2a = w4[128+o], w2b = w4[128+o+1];
            float4 w3a = w4[192+o], w3b = w4[192+o+1];
            float v0 = silu_f(ba.x + d4.x*w0a.x + d4.y*w1a.x + d4.z*w2a.x + d4.w*w3a.x);
            float v1 = silu_f(ba.y + d4.x*w0a.y + d4.y*w1a.y + d4.z*w2a.y + d4.w*w3a.y);
            float v2 = silu_f(ba.z + d4.x*w0a.z + d4.y*w1a.z + d4.z*w2a.z + d4.w*w3a.z);
            float v3 = silu_f(ba.w + d4.x*w0a.w + d4.y*w1a.w + d4.z*w2a.w + d4.w*w3a.w);
            float v4 = silu_f(bb.x + d4.x*w0b.x + d4.y*w1b.x + d4.z*w2b.x + d4.w*w3b.x);
            float v5 = silu_f(bb.y + d4.x*w0b.y + d4.y*w1b.y + d4.z*w2b.y + d4.w*w3b.y);
            float v6 = silu_f(bb.z + d4.x*w0b.z + d4.y*w1b.z + d4.z*w2b.z + d4.w*w3b.z);
            float v7 = silu_f(bb.w + d4.x*w0b.w + d4.y*w1b.w + d4.z*w2b.w + d4.w*w3b.w);
            uint4 o4;
            o4.x = pkr(v0, v1); o4.y = pkr(v2, v3);
            o4.z = pkr(v4, v5); o4.w = pkr(v6, v7);
            fb[(mtf * 8 + wid) * 64 + g * 16 + frf] = o4;
        }
    };
    // E staging: thread handles row=tid>>3, k in [skti*32, skti*32+32)
    auto stage_e = [&](int bsel, const float4* evA, const float4* evB) {
        uint4* eb = ebuf[bsel];
        #pragma unroll
        for (int g = 0; g < 2; ++g) {
            float4 a = evA[g*2], b = evA[g*2+1];
            uint4 o4;
            o4.x = pkr(a.x,a.y); o4.y = pkr(a.z,a.w);
            o4.z = pkr(b.x,b.y); o4.w = pkr(b.z,b.w);
            eb[(smt * 8 + skti) * 64 + g * 16 + sfr] = o4;
        }
        #pragma unroll
        for (int g = 2; g < 4; ++g) {
            float4 a = evB[(g-2)*2], b = evB[(g-2)*2+1];
            uint4 o4;
            o4.x = pkr(a.x,a.y); o4.y = pkr(a.z,a.w);
            o4.z = pkr(b.x,b.y); o4.w = pkr(b.z,b.w);
            eb[(smt * 8 + skti) * 64 + g * 16 + sfr] = o4;
        }
    };

    __syncthreads();   // wf1_s / b1_s ready

    // prologue: stage tile 0 into buf 0
    {
        const int eblk = tbase * 64;
        float4 d4 = *(const float4*)(diff + (size_t)(eblk + lane) * 4);
        const float4* ep = (const float4*)(nbr + (size_t)(eblk + srow) * 256 + skti * 32);
        float4 evA[4] = {ep[0], ep[1], ep[2], ep[3]};
        float4 evB[4] = {ep[4], ep[5], ep[6], ep[7]};
        stage_e(0, evA, evB);
        stage_f(0, d4);
    }
    __syncthreads();

    for (int t = 0; t < TPB_TILES; ++t) {
        const int cur = t & 1;
        const bool more = (t + 1 < TPB_TILES);

        // 1. issue next tile's global loads early (hide HBM under MFMA)
        float4 d4n = (float4){0.f,0.f,0.f,0.f};
        float4 evA[4], evB[4];
        if (more) {
            const int eblk = (tbase + t + 1) * 64;
            d4n = *(const float4*)(diff + (size_t)(eblk + lane) * 4);
            const float4* epn = (const float4*)(nbr + (size_t)(eblk + srow) * 256 + skti * 32);
            evA[0] = epn[0]; evA[1] = epn[1]; evA[2] = epn[2]; evA[3] = epn[3];
            evB[0] = epn[4]; evB[1] = epn[5]; evB[2] = epn[6]; evB[3] = epn[7];
        }

        // 2. MFMA over buf[cur]: 64 ds_read_b128 + 128 MFMA per wave
        {
            const short8* fb = (const short8*)fbuf[cur];
            const short8* eb = (const short8*)ebuf[cur];
            #pragma unroll
            for (int kti = 0; kti < 8; ++kti) {
                #pragma unroll
                for (int mt = 0; mt < 4; ++mt) {
                    short8 aF = fb[(mt * 8 + kti) * 64 + lane];
                    short8 aE = eb[(mt * 8 + kti) * 64 + lane];
                    accP[mt][0] = __builtin_amdgcn_mfma_f32_16x16x32_bf16(aF, bF[kti][0], accP[mt][0], 0, 0, 0);
                    accP[mt][1] = __builtin_amdgcn_mfma_f32_16x16x32_bf16(aF, bF[kti][1], accP[mt][1], 0, 0, 0);
                    accH[mt][0] = __builtin_amdgcn_mfma_f32_16x16x32_bf16(aE, bN[kti][0], accH[mt][0], 0, 0, 0);
                    accH[mt][1] = __builtin_amdgcn_mfma_f32_16x16x32_bf16(aE, bN[kti][1], accH[mt][1], 0, 0, 0);
                }
            }
        }

        // 3. stage next tile into the other buffer
        if (more) {
            stage_e(1 - cur, evA, evB);
            stage_f(1 - cur, d4n);
        }

        // 4. epilogue: gate + 32-row reduction per node, store, re-zero acc
        const int nodeBase = (tbase + t) * 2;
        #pragma unroll
        for (int nd = 0; nd < 2; ++nd) {
            #pragma unroll
            for (int nt = 0; nt < 2; ++nt) {
                float s = 0.f;
                #pragma unroll
                for (int m2 = 0; m2 < 2; ++m2) {
                    const int mt = nd * 2 + m2;
                    #pragma unroll
                    for (int r = 0; r < 4; ++r)
                        s += (accP[mt][nt][r] + vb2[nt]) * (accH[mt][nt][r] + vbn[nt]);
                }
                s += __shfl_xor(s, 16);
                s += __shfl_xor(s, 32);
                if (lane < 16)
                    msg_out[(size_t)(nodeBase + nd) * 256 + wid * 32 + nt * 16 + lane] = s;
            }
        }
        #pragma unroll
        for (int mt = 0; mt < 4; ++mt)
            #pragma unroll
            for (int nt = 0; nt < 2; ++nt) {
                accP[mt][nt] = (f32x4){0.f,0.f,0.f,0.f};
                accH[mt][nt] = (f32x4){0.f,0.f,0.f,0.f};
            }

        __syncthreads();
    }
}

// ---------------------------------------------------------------------------
// Kernel 3: out = silu(h_center @ Wc + bc + msg), msg lives in `out` already.
// ---------------------------------------------------------------------------
__global__ __launch_bounds__(256) void out_kernel(
        const float* __restrict__ hc,     // [N,256]
        const float* __restrict__ bc,     // [256]
        const uint4* __restrict__ wc_g,   // frag bf16, 8192 uint4
        float* __restrict__ out)          // [N,256], contains msg on entry
{
    __shared__ unsigned short a_s[4 * 2 * 64 * 8];    // 8KB
    __shared__ unsigned short wc_s[2 * 16 * 64 * 8];  // 32KB

    const int tid  = threadIdx.x;
    const int lane = tid & 63;
    const int wn   = tid >> 6;        // 0..3
    const int rblk = blockIdx.x * 64;

    f32x4 acc[4][4];
    #pragma unroll
    for (int mt = 0; mt < 4; ++mt)
        #pragma unroll
        for (int nt = 0; nt < 4; ++nt)
            acc[mt][nt] = (f32x4){0.f, 0.f, 0.f, 0.f};

    uint4* af4 = (uint4*)a_s;
    for (int kt2 = 0; kt2 < 4; ++kt2) {
        {
            int row = tid >> 2, quarter = tid & 3;
            const float* src = hc + (size_t)(rblk + row) * 256 + kt2 * 64 + quarter * 16;
            float4 v0 = *(const float4*)(src + 0);
            float4 v1 = *(const float4*)(src + 4);
            float4 v2 = *(const float4*)(src + 8);
            float4 v3 = *(const float4*)(src + 12);
            uint4 p0, p1;
            p0.x = pk2(v0.x, v0.y); p0.y = pk2(v0.z, v0.w);
            p0.z = pk2(v1.x, v1.y); p0.w = pk2(v1.z, v1.w);
            p1.x = pk2(v2.x, v2.y); p1.y = pk2(v2.z, v2.w);
            p1.z = pk2(v3.x, v3.y); p1.w = pk2(v3.z, v3.w);
            int mt = row >> 4, kti = quarter >> 1, fr = row & 15;
            int g0 = (quarter & 1) * 2;
            af4[(mt * 2 + kti) * 64 + g0 * 16 + fr]       = p0;
            af4[(mt * 2 + kti) * 64 + (g0 + 1) * 16 + fr] = p1;
            const uint4* srcw = wc_g + kt2 * 2048;
            uint4* dw = (uint4*)wc_s;
            #pragma unroll
            for (int j = 0; j < 8; ++j)
                dw[j * 256 + tid] = srcw[j * 256 + tid];
        }
        __syncthreads();
        #pragma unroll
        for (int kti = 0; kti < 2; ++kti) {
            short8 b[4];
            #pragma unroll
            for (int nt = 0; nt < 4; ++nt)
                b[nt] = *(const short8*)&wc_s[((kti * 16 + wn * 4 + nt) * 64 + lane) * 8];
            #pragma unroll
            for (int mt = 0; mt < 4; ++mt) {
                short8 a = *(const short8*)&a_s[((mt * 2 + kti) * 64 + lane) * 8];
                #pragma unroll
                for (int nt = 0; nt < 4; ++nt)
                    acc[mt][nt] = __builtin_amdgcn_mfma_f32_16x16x32_bf16(a, b[nt], acc[mt][nt], 0, 0, 0);
            }
        }
        __syncthreads();
    }

    #pragma unroll
    for (int mt = 0; mt < 4; ++mt)
        #pragma unroll
        for (int nt = 0; nt < 4; ++nt)
            #pragma unroll
            for (int r = 0; r < 4; ++r) {
                int grow = rblk + mt * 16 + ((lane >> 4) << 2) + r;
                int col  = wn * 64 + nt * 16 + (lane & 15);
                size_t idx = (size_t)grow * 256 + col;
                float v = acc[mt][nt][r] + bc[col] + out[idx];
                out[idx] = silu_f(v);
            }
}

// ---------------------------------------------------------------------------
extern "C" void kernel_launch(void* const* d_in, const int* in_sizes, int n_in,
                              void* d_out, int out_size, void* d_ws, size_t ws_size,
                              hipStream_t stream) {
    const float* h_center    = (const float*)d_in[0];
    const float* h_neighbors = (const float*)d_in[1];
    const float* differences = (const float*)d_in[2];
    const float* W_f1        = (const float*)d_in[3];
    const float* b_f1        = (const float*)d_in[4];
    const float* W_f2        = (const float*)d_in[5];
    const float* b_f2        = (const float*)d_in[6];
    const float* W_nb        = (const float*)d_in[7];
    const float* b_nb        = (const float*)d_in[8];
    const float* W_c         = (const float*)d_in[9];
    const float* b_c         = (const float*)d_in[10];
    float* out = (float*)d_out;

    uint4* ws4 = (uint4*)d_ws;            // 24576 * 16B = 384KB of scratch
    const uint4* wf2_ws = ws4;            // [0, 8192)
    const uint4* wnb_ws = ws4 + 8192;     // [8192, 16384)
    const uint4* wc_ws  = ws4 + 16384;    // [16384, 24576)

    prep_weights<<<96, 256, 0, stream>>>(W_f2, W_nb, W_c, ws4);
    msg_kernel<<<NN / 2 / TPB_TILES, 512, 0, stream>>>(
        h_neighbors, differences, W_f1, b_f1, b_f2, b_nb, wf2_ws, wnb_ws, out);
    out_kernel<<<NN / 64, 256, 0, stream>>>(h_center, b_c, wc_ws, out);
}

// Round 4
// 834.228 us; speedup vs baseline: 1.0138x; 1.0138x over previous
//
#include <hip/hip_runtime.h>
#include <hip/hip_bf16.h>
#include <stdint.h>

// Problem constants
#define NN 32768
#define KNBR 32

typedef __attribute__((ext_vector_type(8))) short short8;
typedef __attribute__((ext_vector_type(4))) float f32x4;

__device__ __forceinline__ unsigned int f2bf(float x) {
    union { float f; unsigned int u; } c; c.f = x;
    return (c.u + 0x7FFFu + ((c.u >> 16) & 1u)) >> 16;
}
__device__ __forceinline__ unsigned int pk2(float a, float b) {
    return f2bf(a) | (f2bf(b) << 16);
}
// cheap round-half-up bf16 pack (bias negligible vs threshold; r1/r2 absmax 0.125)
__device__ __forceinline__ unsigned int pkr(float a, float b) {
    unsigned ua = __float_as_uint(a) + 0x8000u;
    unsigned ub = __float_as_uint(b) + 0x8000u;
    return (ua >> 16) | (ub & 0xFFFF0000u);
}
__device__ __forceinline__ float silu_f(float x) {
    return x / (1.0f + __expf(-x));
}

// ---------------------------------------------------------------------------
// Kernel 1: convert W_f2, W_nb, W_c (f32 row-major [256][256]) into bf16
// MFMA B-fragment layout: frag q = (kt*16 + nt)*64 + lane holds
// B[k = kt*32 + (lane>>4)*8 + i][col = nt*16 + (lane&15)], i=0..7, 16B/frag.
// ---------------------------------------------------------------------------
__global__ void prep_weights(const float* __restrict__ Wf2,
                             const float* __restrict__ Wnb,
                             const float* __restrict__ Wc,
                             uint4* __restrict__ ws_out) {
    int t = blockIdx.x * 256 + threadIdx.x;   // 0..24575
    int w = t >> 13;
    int q = t & 8191;
    int kt = q >> 10;
    int nt = (q >> 6) & 15;
    int lane = q & 63;
    int k0 = kt * 32 + ((lane >> 4) << 3);
    int col = nt * 16 + (lane & 15);
    const float* src = (w == 0) ? Wf2 : (w == 1) ? Wnb : Wc;
    const float* p = src + (size_t)k0 * 256 + col;
    uint4 o;
    o.x = pk2(p[0],        p[256]);
    o.y = pk2(p[512],      p[768]);
    o.z = pk2(p[1024],     p[1280]);
    o.w = pk2(p[1536],     p[1792]);
    ws_out[t] = o;
}

// ---------------------------------------------------------------------------
// Kernel 2: fused edge pipeline, 1024 threads = 16 waves (2M x 8N), tile =
// 128 edge rows x 256 cols, K-step = 32, ONE barrier per step.
// Wave (wm,wn): rows [wm*64,+64), cols [wn*32,+32); dual acc (Phi,H) = 64 reg.
// Waves 0-7 stage f = silu(diff@Wf1+b1) (VALU); waves 8-15 stage E (HBM).
// Weights prefetched 1 step ahead from L2-resident ws (double-buffered LDS).
// ---------------------------------------------------------------------------
__global__ __launch_bounds__(1024, 4) void msg_kernel(
        const float* __restrict__ nbr,    // h_neighbors [N*K, 256]
        const float* __restrict__ diff,   // differences [N*K, 4]
        const float* __restrict__ Wf1,    // [4,256]
        const float* __restrict__ b1,     // [256]
        const float* __restrict__ b2,     // b_f2 [256]
        const float* __restrict__ bnb,    // b_nb [256]
        const uint4* __restrict__ wf2_g,  // frag bf16, 8192 uint4
        const uint4* __restrict__ wnb_g,  // frag bf16, 8192 uint4
        float* __restrict__ msg_out)      // [N,256] f32
{
    __shared__ uint4 fbuf[2][512];     // 16KB  f A-frags (128r x 32k)
    __shared__ uint4 ebuf[2][512];     // 16KB  E A-frags
    __shared__ uint4 w2buf[2][1024];   // 32KB  Wf2 B-frags (32k x 256c)
    __shared__ uint4 wnbuf[2][1024];   // 32KB  Wnb B-frags
    __shared__ float wf1_s[1024];      // 4KB
    __shared__ float b1_s[256];        // 1KB   -> total 101KB

    const int tid  = threadIdx.x;
    const int lane = tid & 63;
    const int wid  = tid >> 6;       // 0..15
    const int wm   = wid >> 3;       // 0..1
    const int wn   = wid & 7;        // 0..7
    const bool isF = (wid < 8);      // staging role (wave-uniform)
    const int smt  = isF ? wid : (wid - 8);        // 0..7 : 16-row group
    const int srow = smt * 16 + (lane & 15);       // 0..127
    const int sk   = (lane >> 4) << 3;             // 0,8,16,24
    const size_t rbase = (size_t)blockIdx.x * 128;

    wf1_s[tid] = Wf1[tid];
    if (tid < 256) b1_s[tid] = b1[tid];

    float4 d4 = make_float4(0.f, 0.f, 0.f, 0.f);
    if (isF) d4 = *(const float4*)(diff + (rbase + srow) * 4);

    float vb2[2], vbn[2];
    #pragma unroll
    for (int nt = 0; nt < 2; ++nt) {
        const int col = wn * 32 + nt * 16 + (lane & 15);
        vb2[nt] = b2[col];
        vbn[nt] = bnb[col];
    }

    __syncthreads();   // wf1_s / b1_s ready

    // f staging: thread computes 8 silu values for (srow, k = kt*32+sk .. +8)
    auto fvals = [&](int kt) -> uint4 {
        const int o = (kt * 32 + sk) >> 2;   // float4 index (row stride 64)
        const float4* w4 = (const float4*)wf1_s;
        const float4* b4 = (const float4*)b1_s;
        float4 ba  = b4[o],       bb  = b4[o + 1];
        float4 w0a = w4[o],       w0b = w4[o + 1];
        float4 w1a = w4[64 + o],  w1b = w4[64 + o + 1];
        float4 w2a = w4[128 + o], w2b = w4[128 + o + 1];
        float4 w3a = w4[192 + o], w3b = w4[192 + o + 1];
        float v0 = silu_f(ba.x + d4.x*w0a.x + d4.y*w1a.x + d4.z*w2a.x + d4.w*w3a.x);
        float v1 = silu_f(ba.y + d4.x*w0a.y + d4.y*w1a.y + d4.z*w2a.y + d4.w*w3a.y);
        float v2 = silu_f(ba.z + d4.x*w0a.z + d4.y*w1a.z + d4.z*w2a.z + d4.w*w3a.z);
        float v3 = silu_f(ba.w + d4.x*w0a.w + d4.y*w1a.w + d4.z*w2a.w + d4.w*w3a.w);
        float v4 = silu_f(bb.x + d4.x*w0b.x + d4.y*w1b.x + d4.z*w2b.x + d4.w*w3b.x);
        float v5 = silu_f(bb.y + d4.x*w0b.y + d4.y*w1b.y + d4.z*w2b.y + d4.w*w3b.y);
        float v6 = silu_f(bb.z + d4.x*w0b.z + d4.y*w1b.z + d4.z*w2b.z + d4.w*w3b.z);
        float v7 = silu_f(bb.w + d4.x*w0b.w + d4.y*w1b.w + d4.z*w2b.w + d4.w*w3b.w);
        uint4 r;
        r.x = pkr(v0, v1); r.y = pkr(v2, v3);
        r.z = pkr(v4, v5); r.w = pkr(v6, v7);
        return r;
    };
    // E staging: thread loads 8 f32 (32B, 4-lane-group 128B coalesced) -> bf16
    auto evals = [&](int kt) -> uint4 {
        const float* p = nbr + (rbase + srow) * 256 + kt * 32 + sk;
        float4 a = *(const float4*)p;
        float4 b = *(const float4*)(p + 4);
        uint4 r;
        r.x = pkr(a.x, a.y); r.y = pkr(a.z, a.w);
        r.z = pkr(b.x, b.y); r.w = pkr(b.z, b.w);
        return r;
    };
    auto stage_act = [&](int bsel, uint4 v) {
        if (isF) fbuf[bsel][tid] = v;            // slot = smt*64 + lane
        else     ebuf[bsel][tid - 512] = v;
    };

    // prologue: step 0 into buffer 0
    {
        uint4 w2v = wf2_g[tid];
        uint4 wnv = wnb_g[tid];
        uint4 av  = isF ? fvals(0) : evals(0);
        w2buf[0][tid] = w2v;
        wnbuf[0][tid] = wnv;
        stage_act(0, av);
    }
    __syncthreads();

    f32x4 accP[4][2], accH[4][2];
    #pragma unroll
    for (int mt = 0; mt < 4; ++mt)
        #pragma unroll
        for (int nt = 0; nt < 2; ++nt) {
            accP[mt][nt] = (f32x4){0.f, 0.f, 0.f, 0.f};
            accH[mt][nt] = (f32x4){0.f, 0.f, 0.f, 0.f};
        }

    for (int kt = 0; kt < 8; ++kt) {
        const int cur = kt & 1;
        const bool more = (kt < 7);
        uint4 w2n, wnn, avn;
        if (more) {   // issue next step's loads early (weights L2, E HBM)
            w2n = wf2_g[(kt + 1) * 1024 + tid];
            wnn = wnb_g[(kt + 1) * 1024 + tid];
            avn = isF ? fvals(kt + 1) : evals(kt + 1);
        }

        // MFMA over buf[cur]: per wave 8 A + 4 B ds_read_b128, 16 MFMA
        {
            const short8* fb  = (const short8*)fbuf[cur];
            const short8* eb  = (const short8*)ebuf[cur];
            const short8* w2p = (const short8*)w2buf[cur];
            const short8* wnp = (const short8*)wnbuf[cur];
            short8 bF0 = w2p[(wn * 2 + 0) * 64 + lane];
            short8 bF1 = w2p[(wn * 2 + 1) * 64 + lane];
            short8 bN0 = wnp[(wn * 2 + 0) * 64 + lane];
            short8 bN1 = wnp[(wn * 2 + 1) * 64 + lane];
            #pragma unroll
            for (int mt = 0; mt < 4; ++mt) {
                short8 aF = fb[(wm * 4 + mt) * 64 + lane];
                short8 aE = eb[(wm * 4 + mt) * 64 + lane];
                accP[mt][0] = __builtin_amdgcn_mfma_f32_16x16x32_bf16(aF, bF0, accP[mt][0], 0, 0, 0);
                accP[mt][1] = __builtin_amdgcn_mfma_f32_16x16x32_bf16(aF, bF1, accP[mt][1], 0, 0, 0);
                accH[mt][0] = __builtin_amdgcn_mfma_f32_16x16x32_bf16(aE, bN0, accH[mt][0], 0, 0, 0);
                accH[mt][1] = __builtin_amdgcn_mfma_f32_16x16x32_bf16(aE, bN1, accH[mt][1], 0, 0, 0);
            }
        }

        if (more) {
            w2buf[cur ^ 1][tid] = w2n;
            wnbuf[cur ^ 1][tid] = wnn;
            stage_act(cur ^ 1, avn);
        }
        __syncthreads();
    }

    // epilogue: gate + per-node 32-row reduction
    // C-frag: local row = (wm*4+mt_l)*16... per wave: row = mt*16+(lane>>4)*4+r
    #pragma unroll
    for (int nd = 0; nd < 2; ++nd) {
        const size_t node = (size_t)blockIdx.x * 4 + wm * 2 + nd;
        #pragma unroll
        for (int nt = 0; nt < 2; ++nt) {
            float s = 0.f;
            #pragma unroll
            for (int m2 = 0; m2 < 2; ++m2) {
                const int mt = nd * 2 + m2;
                #pragma unroll
                for (int r = 0; r < 4; ++r)
                    s += (accP[mt][nt][r] + vb2[nt]) * (accH[mt][nt][r] + vbn[nt]);
            }
            s += __shfl_xor(s, 16);
            s += __shfl_xor(s, 32);
            if (lane < 16)
                msg_out[node * 256 + wn * 32 + nt * 16 + lane] = s;
        }
    }
}

// ---------------------------------------------------------------------------
// Kernel 3: out = silu(h_center @ Wc + bc + msg), msg lives in `out` already.
// ---------------------------------------------------------------------------
__global__ __launch_bounds__(256) void out_kernel(
        const float* __restrict__ hc,     // [N,256]
        const float* __restrict__ bc,     // [256]
        const uint4* __restrict__ wc_g,   // frag bf16, 8192 uint4
        float* __restrict__ out)          // [N,256], contains msg on entry
{
    __shared__ unsigned short a_s[4 * 2 * 64 * 8];    // 8KB
    __shared__ unsigned short wc_s[2 * 16 * 64 * 8];  // 32KB

    const int tid  = threadIdx.x;
    const int lane = tid & 63;
    const int wn   = tid >> 6;        // 0..3
    const int rblk = blockIdx.x * 64;

    f32x4 acc[4][4];
    #pragma unroll
    for (int mt = 0; mt < 4; ++mt)
        #pragma unroll
        for (int nt = 0; nt < 4; ++nt)
            acc[mt][nt] = (f32x4){0.f, 0.f, 0.f, 0.f};

    uint4* af4 = (uint4*)a_s;
    for (int kt2 = 0; kt2 < 4; ++kt2) {
        {
            int row = tid >> 2, quarter = tid & 3;
            const float* src = hc + (size_t)(rblk + row) * 256 + kt2 * 64 + quarter * 16;
            float4 v0 = *(const float4*)(src + 0);
            float4 v1 = *(const float4*)(src + 4);
            float4 v2 = *(const float4*)(src + 8);
            float4 v3 = *(const float4*)(src + 12);
            uint4 p0, p1;
            p0.x = pk2(v0.x, v0.y); p0.y = pk2(v0.z, v0.w);
            p0.z = pk2(v1.x, v1.y); p0.w = pk2(v1.z, v1.w);
            p1.x = pk2(v2.x, v2.y); p1.y = pk2(v2.z, v2.w);
            p1.z = pk2(v3.x, v3.y); p1.w = pk2(v3.z, v3.w);
            int mt = row >> 4, kti = quarter >> 1, fr = row & 15;
            int g0 = (quarter & 1) * 2;
            af4[(mt * 2 + kti) * 64 + g0 * 16 + fr]       = p0;
            af4[(mt * 2 + kti) * 64 + (g0 + 1) * 16 + fr] = p1;
            const uint4* srcw = wc_g + kt2 * 2048;
            uint4* dw = (uint4*)wc_s;
            #pragma unroll
            for (int j = 0; j < 8; ++j)
                dw[j * 256 + tid] = srcw[j * 256 + tid];
        }
        __syncthreads();
        #pragma unroll
        for (int kti = 0; kti < 2; ++kti) {
            short8 b[4];
            #pragma unroll
            for (int nt = 0; nt < 4; ++nt)
                b[nt] = *(const short8*)&wc_s[((kti * 16 + wn * 4 + nt) * 64 + lane) * 8];
            #pragma unroll
            for (int mt = 0; mt < 4; ++mt) {
                short8 a = *(const short8*)&a_s[((mt * 2 + kti) * 64 + lane) * 8];
                #pragma unroll
                for (int nt = 0; nt < 4; ++nt)
                    acc[mt][nt] = __builtin_amdgcn_mfma_f32_16x16x32_bf16(a, b[nt], acc[mt][nt], 0, 0, 0);
            }
        }
        __syncthreads();
    }

    #pragma unroll
    for (int mt = 0; mt < 4; ++mt)
        #pragma unroll
        for (int nt = 0; nt < 4; ++nt)
            #pragma unroll
            for (int r = 0; r < 4; ++r) {
                int grow = rblk + mt * 16 + ((lane >> 4) << 2) + r;
                int col  = wn * 64 + nt * 16 + (lane & 15);
                size_t idx = (size_t)grow * 256 + col;
                float v = acc[mt][nt][r] + bc[col] + out[idx];
                out[idx] = silu_f(v);
            }
}

// ---------------------------------------------------------------------------
extern "C" void kernel_launch(void* const* d_in, const int* in_sizes, int n_in,
                              void* d_out, int out_size, void* d_ws, size_t ws_size,
                              hipStream_t stream) {
    const float* h_center    = (const float*)d_in[0];
    const float* h_neighbors = (const float*)d_in[1];
    const float* differences = (const float*)d_in[2];
    const float* W_f1        = (const float*)d_in[3];
    const float* b_f1        = (const float*)d_in[4];
    const float* W_f2        = (const float*)d_in[5];
    const float* b_f2        = (const float*)d_in[6];
    const float* W_nb        = (const float*)d_in[7];
    const float* b_nb        = (const float*)d_in[8];
    const float* W_c         = (const float*)d_in[9];
    const float* b_c         = (const float*)d_in[10];
    float* out = (float*)d_out;

    uint4* ws4 = (uint4*)d_ws;            // 24576 * 16B = 384KB of scratch
    const uint4* wf2_ws = ws4;            // [0, 8192)
    const uint4* wnb_ws = ws4 + 8192;     // [8192, 16384)
    const uint4* wc_ws  = ws4 + 16384;    // [16384, 24576)

    prep_weights<<<96, 256, 0, stream>>>(W_f2, W_nb, W_c, ws4);
    msg_kernel<<<(NN * KNBR) / 128, 1024, 0, stream>>>(
        h_neighbors, differences, W_f1, b_f1, b_f2, b_nb, wf2_ws, wnb_ws, out);
    out_kernel<<<NN / 64, 256, 0, stream>>>(h_center, b_c, wc_ws, out);
}